// Round 7
// baseline (3444.546 us; speedup 1.0000x reference)
//
#include <hip/hip_runtime.h>
#include <hip/hip_bf16.h>

#define BB   8
#define HGT  128
#define WID  128
#define CC   192
#define LLEN (HGT*WID)        // 16384
#define MM   (BB*LLEN)        // 131072
#define NF   388              // 2C + FL + 1
#define HIDN 768

typedef unsigned short us16;
typedef __attribute__((ext_vector_type(8))) short bf16x8;
typedef __attribute__((ext_vector_type(4))) float f32x4;

__device__ __forceinline__ float bf2f(us16 u) {
    return __uint_as_float(((unsigned int)u) << 16);
}
__device__ __forceinline__ us16 f2bf(float f) {
    unsigned int x = __float_as_uint(f);
    x = (x + 0x7fffu + ((x >> 16) & 1u)) >> 16;
    return (us16)x;
}
// fast gelu: tanh form via exp2-backed __expf
__device__ __forceinline__ float gelu_f(float x) {
    float u = 0.7978845608f * x * (1.0f + 0.044715f * x * x);
    float e = __expf(fminf(2.0f * u, 30.0f));
    return 0.5f * x * (1.0f + (e - 1.0f) / (e + 1.0f));
}

__device__ __forceinline__ void gload_lds16(const void* g, void* l) {
    __builtin_amdgcn_global_load_lds(
        (const __attribute__((address_space(1))) void*)g,
        (__attribute__((address_space(3))) void*)l, 16, 0, 0);
}

// ---------------- Weight convert: fp32 -> bf16, transposed ----------
__global__ __launch_bounds__(256) void wcvt_kernel(const float* __restrict__ f_w,
        const float* __restrict__ h_w, const float* __restrict__ proj_w,
        const float* __restrict__ fc1_w, const float* __restrict__ fc2_w,
        const float* __restrict__ fk0, const float* __restrict__ fk1,
        const float* __restrict__ fk2,
        us16* __restrict__ fwT, us16* __restrict__ hwB, us16* __restrict__ projT,
        us16* __restrict__ w1T, us16* __restrict__ w2T,
        us16* __restrict__ kw0T, us16* __restrict__ kw1T, us16* __restrict__ kw2T) {
    int i = blockIdx.x * 256 + threadIdx.x;
    if (i < 86016) {                       // fwT: 448 x 192 (pad rows >= 388 = 0)
        int n = i / 192, k = i % 192;
        fwT[i] = (n < NF) ? f2bf(f_w[k * NF + n]) : (us16)0;
        return;
    }
    i -= 86016;
    if (i < 36864) { hwB[i] = f2bf(h_w[i]); return; }       // h_w[o][c] is already [N][K]
    i -= 36864;
    if (i < 36864) { int n = i / 192, k = i % 192; projT[i] = f2bf(proj_w[k * CC + n]); return; }
    i -= 36864;
    if (i < 147456) { int n = i / 192, k = i % 192; w1T[i] = f2bf(fc1_w[k * HIDN + n]); return; }
    i -= 147456;
    if (i < 147456) { int n = i / 768, k = i % 768; w2T[i] = f2bf(fc2_w[k * CC + n]); return; }
    i -= 147456;
    if (i < 1728)  { int kyx = i / 192, c = i % 192; kw0T[i] = f2bf(fk0[c * 9 + kyx]);  return; }
    i -= 1728;
    if (i < 4800)  { int kyx = i / 192, c = i % 192; kw1T[i] = f2bf(fk1[c * 25 + kyx]); return; }
    i -= 4800;
    if (i < 9408)  { int kyx = i / 192, c = i % 192; kw2T[i] = f2bf(fk2[c * 49 + kyx]); return; }
}

// ---------------- LayerNorm: fp32 in -> bf16 out (wave per row) ----------------
__global__ __launch_bounds__(256) void ln_kernel(const float* __restrict__ in,
                                                 const float* __restrict__ g,
                                                 const float* __restrict__ b,
                                                 us16* __restrict__ out) {
    int wid  = threadIdx.x >> 6;
    int lane = threadIdx.x & 63;
    int row  = blockIdx.x * 4 + wid;
    const float* p = in + (size_t)row * CC;
    float v0 = p[lane], v1 = p[lane + 64], v2 = p[lane + 128];
    float s1 = v0 + v1 + v2;
    float s2 = v0*v0 + v1*v1 + v2*v2;
    for (int o = 32; o; o >>= 1) { s1 += __shfl_xor(s1, o); s2 += __shfl_xor(s2, o); }
    float m   = s1 * (1.0f / 192.0f);
    float var = s2 * (1.0f / 192.0f) - m * m;
    float inv = rsqrtf(var + 1e-5f);
    us16* q = out + (size_t)row * CC;
    q[lane]       = f2bf((v0 - m) * inv * g[lane]       + b[lane]);
    q[lane + 64]  = f2bf((v1 - m) * inv * g[lane + 64]  + b[lane + 64]);
    q[lane + 128] = f2bf((v2 - m) * inv * g[lane + 128] + b[lane + 128]);
}

// ---------------- MFMA GEMM: LDS-staged A, K=192, 128x64 tile, 4 waves --------
template<int MODE>
__global__ __launch_bounds__(256) void mgemm_kernel(const us16* __restrict__ A,
        const us16* __restrict__ Bt, const float* __restrict__ bias,
        us16* __restrict__ out_q, us16* __restrict__ out_ctx, us16* __restrict__ out_g,
        const us16* __restrict__ q_in, const us16* __restrict__ gates_in,
        const float* __restrict__ hg, const float* __restrict__ x_in,
        float* __restrict__ out_f) {
    __shared__ __align__(16) char Asm[128 * 384];
    constexpr int NT = (MODE == 0) ? 7 : 3;
    int id  = blockIdx.x;
    int xcd = id & 7;
    int s   = id >> 3;
    int mt  = xcd * 128 + s / NT;          // all N-tiles of an M-tile on one XCD
    int nt  = s % NT;
    int m0 = mt * 128, n0 = nt * 64;
    int tid = threadIdx.x, lane = tid & 63, w = tid >> 6;
    int wm = w >> 1, wn = w & 1, g = lane >> 4, lr = lane & 15;

    const char* Agl = (const char*)(A + (size_t)m0 * CC);
    #pragma unroll
    for (int i = 0; i < 12; i++) {
        int wl   = w * 12 + i;                 // 0..47
        int byte = wl * 1024 + lane * 16;
        int row  = byte / 384;
        int off  = byte - row * 384;
        int soff = off ^ ((row & 7) << 4);
        gload_lds16(Agl + (size_t)row * 384 + soff, Asm + wl * 1024);
    }
    const us16* Bb = Bt + (size_t)(n0 + wn * 32 + lr) * CC;
    bf16x8 bfr[6][2];
    #pragma unroll
    for (int kk = 0; kk < 6; kk++)
        #pragma unroll
        for (int j = 0; j < 2; j++)
            bfr[kk][j] = *(const bf16x8*)(Bb + (size_t)j * 16 * CC + kk * 32 + g * 8);

    __syncthreads();

    f32x4 acc[4][2] = {};
    #pragma unroll
    for (int kk = 0; kk < 6; kk++) {
        int k2 = (kk * 32 + g * 8) * 2;
        bf16x8 a[4];
        #pragma unroll
        for (int i = 0; i < 4; i++) {
            int row = wm * 64 + i * 16 + lr;
            a[i] = *(const bf16x8*)(Asm + row * 384 + (k2 ^ ((row & 7) << 4)));
        }
        #pragma unroll
        for (int j = 0; j < 2; j++) {
            acc[0][j] = __builtin_amdgcn_mfma_f32_16x16x32_bf16(a[0], bfr[kk][j], acc[0][j], 0, 0, 0);
            acc[1][j] = __builtin_amdgcn_mfma_f32_16x16x32_bf16(a[1], bfr[kk][j], acc[1][j], 0, 0, 0);
            acc[2][j] = __builtin_amdgcn_mfma_f32_16x16x32_bf16(a[2], bfr[kk][j], acc[2][j], 0, 0, 0);
            acc[3][j] = __builtin_amdgcn_mfma_f32_16x16x32_bf16(a[3], bfr[kk][j], acc[3][j], 0, 0, 0);
        }
    }
    int orow = m0 + wm * 64;
    #pragma unroll
    for (int i = 0; i < 4; i++) {
        #pragma unroll
        for (int j = 0; j < 2; j++) {
            int ncol = n0 + wn * 32 + j * 16;
            int cc   = ncol + lr;
            #pragma unroll
            for (int r = 0; r < 4; r++) {
                int row = orow + i * 16 + g * 4 + r;
                float v = acc[i][j][r];
                if (MODE == 0) {
                    if (ncol < 192)      out_q[(size_t)row * CC + cc]          = f2bf(v + bias[cc]);
                    else if (ncol < 384) out_ctx[(size_t)row * CC + (cc - 192)] = f2bf(v + bias[cc]);
                    else if (cc < NF)    out_g[(size_t)row * 4 + (cc - 384)]    = f2bf(v + bias[cc]);
                } else if (MODE == 1) {
                    int bidx = row >> 14;
                    float val = v + bias[cc] + bf2f(gates_in[(size_t)row * 4 + 3]) * hg[bidx * CC + cc];
                    val *= bf2f(q_in[(size_t)row * CC + cc]);
                    out_q[(size_t)row * CC + cc] = f2bf(val);
                } else {
                    out_f[(size_t)row * CC + cc] = v + bias[cc] + x_in[(size_t)row * CC + cc];
                }
            }
        }
    }
}

// ---------------- Fused focal conv chain: conv3->conv5->conv7 in LDS ----------
// Block = 32x32 pixel tile x 8 channels. ctx_all accumulated in-register;
// conv7 plane never hits HBM (per-block partial sums for the global mean).
__global__ __launch_bounds__(256, 2) void fconv_kernel(const us16* __restrict__ in,
        us16* __restrict__ ctx_all, const us16* __restrict__ gates,
        const us16* __restrict__ kw0T, const us16* __restrict__ kw1T,
        const us16* __restrict__ kw2T, float* __restrict__ partial) {
    __shared__ __align__(16) us16 bufA[44 * 44 * 8];   // input; later c5 overlay
    __shared__ __align__(16) us16 bufB[42 * 42 * 8];   // c3
    __shared__ us16 w3s[72], w5s[200], w7s[392];
    __shared__ float wsum[4][8];
    int tid = threadIdx.x;
    int id  = blockIdx.x;
    int swz = (id & 7) * 384 + (id >> 3);     // XCD-chunked: each XCD = 1 image
    int cg  = swz % 24;
    int t   = swz / 24;
    int tx  = t & 3, ty = (t >> 2) & 3, b = t >> 4;
    int ox = tx * 32, oy = ty * 32;

    if (tid < 72)  w3s[tid] = kw0T[(tid >> 3) * CC + cg * 8 + (tid & 7)];
    if (tid < 200) w5s[tid] = kw1T[(tid >> 3) * CC + cg * 8 + (tid & 7)];
    for (int i = tid; i < 392; i += 256) w7s[i] = kw2T[(i >> 3) * CC + cg * 8 + (i & 7)];

    // ---- stage 1: load 44x44 input region (zero-padded) ----
    const us16* inb = in + (size_t)b * LLEN * CC + cg * 8;
    for (int i = tid; i < 1936; i += 256) {
        int ryy = i / 44, rxx = i - ryy * 44;
        int gy = oy + ryy - 6, gx = ox + rxx - 6;
        bf16x8 v = {};
        if (gy >= 0 && gy < 128 && gx >= 0 && gx < 128)
            v = *(const bf16x8*)(inb + (size_t)(gy * WID + gx) * CC);
        *(bf16x8*)(bufA + i * 8) = v;
    }
    __syncthreads();

    // ---- stage 2: conv3 over 42x42 -> bufB (0 outside image) ----
    for (int it = 0; it < 2; it++) {
        int tt = tid + it * 256;
        if (tt < 462) {
            int ry  = tt / 11 + 1;
            int rx0 = (tt - (ry - 1) * 11) * 4 + 1;
            float acc[4][8] = {};
            #pragma unroll
            for (int ky = 0; ky < 3; ky++) {
                int ryy = ry + ky - 1;
                float rv[6][8];
                #pragma unroll
                for (int i2 = 0; i2 < 6; i2++) {
                    int rxx = rx0 - 1 + i2;
                    if (rxx < 44) {
                        bf16x8 v = *(const bf16x8*)(bufA + (ryy * 44 + rxx) * 8);
                        #pragma unroll
                        for (int j = 0; j < 8; j++) rv[i2][j] = bf2f((us16)v[j]);
                    } else {
                        #pragma unroll
                        for (int j = 0; j < 8; j++) rv[i2][j] = 0.0f;
                    }
                }
                #pragma unroll
                for (int kx = 0; kx < 3; kx++) {
                    float w[8];
                    #pragma unroll
                    for (int j = 0; j < 8; j++) w[j] = bf2f(w3s[(ky * 3 + kx) * 8 + j]);
                    #pragma unroll
                    for (int px = 0; px < 4; px++)
                        #pragma unroll
                        for (int j = 0; j < 8; j++)
                            acc[px][j] += rv[kx + px][j] * w[j];
                }
            }
            int gy = oy + ry - 6;
            bool yin = (gy >= 0 && gy < 128);
            #pragma unroll
            for (int px = 0; px < 4; px++) {
                int rx = rx0 + px;
                if (rx < 43) {
                    int gx = ox + rx - 6;
                    bool inimg = yin && gx >= 0 && gx < 128;
                    bf16x8 o;
                    #pragma unroll
                    for (int j = 0; j < 8; j++)
                        o[j] = (short)(inimg ? f2bf(gelu_f(acc[px][j])) : (us16)0);
                    *(bf16x8*)(bufB + ((ry - 1) * 42 + (rx - 1)) * 8) = o;
                }
            }
        }
    }
    __syncthreads();

    // ---- stage 3: conv5 over 38x38 -> bufA overlay (0 outside image) ----
    for (int it = 0; it < 2; it++) {
        int tt = tid + it * 256;
        if (tt < 380) {
            int ry  = tt / 10 + 3;
            int rx0 = (tt - (ry - 3) * 10) * 4 + 3;
            float acc[4][8] = {};
            #pragma unroll
            for (int ky = 0; ky < 5; ky++) {
                int ryy = ry + ky - 2;
                float rv[8][8];
                #pragma unroll
                for (int i2 = 0; i2 < 8; i2++) {
                    int rxx = rx0 - 2 + i2;
                    if (rxx <= 42) {
                        bf16x8 v = *(const bf16x8*)(bufB + ((ryy - 1) * 42 + (rxx - 1)) * 8);
                        #pragma unroll
                        for (int j = 0; j < 8; j++) rv[i2][j] = bf2f((us16)v[j]);
                    } else {
                        #pragma unroll
                        for (int j = 0; j < 8; j++) rv[i2][j] = 0.0f;
                    }
                }
                #pragma unroll
                for (int kx = 0; kx < 5; kx++) {
                    float w[8];
                    #pragma unroll
                    for (int j = 0; j < 8; j++) w[j] = bf2f(w5s[(ky * 5 + kx) * 8 + j]);
                    #pragma unroll
                    for (int px = 0; px < 4; px++)
                        #pragma unroll
                        for (int j = 0; j < 8; j++)
                            acc[px][j] += rv[kx + px][j] * w[j];
                }
            }
            int gy = oy + ry - 6;
            bool yin = (gy >= 0 && gy < 128);
            #pragma unroll
            for (int px = 0; px < 4; px++) {
                int rx = rx0 + px;
                if (rx < 41) {
                    int gx = ox + rx - 6;
                    bool inimg = yin && gx >= 0 && gx < 128;
                    bf16x8 o;
                    #pragma unroll
                    for (int j = 0; j < 8; j++)
                        o[j] = (short)(inimg ? f2bf(gelu_f(acc[px][j])) : (us16)0);
                    *(bf16x8*)(bufA + ((ry - 3) * 38 + (rx - 3)) * 8) = o;
                }
            }
        }
    }
    __syncthreads();

    // ---- stage 4: conv7 central 32x32 + gated ctx_all + mean partials ----
    {
        int ry  = (tid >> 3) + 6;
        int rx0 = (tid & 7) * 4 + 6;
        float acc[4][8] = {};
        for (int ky = 0; ky < 7; ky++) {
            int ryy = ry + ky - 3;
            float rv[10][8];
            #pragma unroll
            for (int i2 = 0; i2 < 10; i2++) {
                int rxx = rx0 - 3 + i2;
                bf16x8 v = *(const bf16x8*)(bufA + ((ryy - 3) * 38 + (rxx - 3)) * 8);
                #pragma unroll
                for (int j = 0; j < 8; j++) rv[i2][j] = bf2f((us16)v[j]);
            }
            #pragma unroll
            for (int kx = 0; kx < 7; kx++) {
                float w[8];
                #pragma unroll
                for (int j = 0; j < 8; j++) w[j] = bf2f(w7s[(ky * 7 + kx) * 8 + j]);
                #pragma unroll
                for (int px = 0; px < 4; px++)
                    #pragma unroll
                    for (int j = 0; j < 8; j++)
                        acc[px][j] += rv[kx + px][j] * w[j];
            }
        }
        float csum[8] = {};
        int gy = oy + ry - 6;
        #pragma unroll
        for (int px = 0; px < 4; px++) {
            int rx = rx0 + px;
            int gx = ox + rx - 6;
            int pix = (b * HGT + gy) * WID + gx;
            uint2 gv = *(const uint2*)(gates + (size_t)pix * 4);
            float g0 = bf2f((us16)(gv.x & 0xffffu));
            float g1 = bf2f((us16)(gv.x >> 16));
            float g2 = bf2f((us16)(gv.y & 0xffffu));
            bf16x8 c3v = *(const bf16x8*)(bufB + ((ry - 1) * 42 + (rx - 1)) * 8);
            bf16x8 c5v = *(const bf16x8*)(bufA + ((ry - 3) * 38 + (rx - 3)) * 8);
            bf16x8 o;
            #pragma unroll
            for (int j = 0; j < 8; j++) {
                float c7 = gelu_f(acc[px][j]);
                csum[j] += c7;
                float ca = g0 * bf2f((us16)c3v[j]) + g1 * bf2f((us16)c5v[j]) + g2 * c7;
                o[j] = (short)f2bf(ca);
            }
            *(bf16x8*)(ctx_all + (size_t)pix * CC + cg * 8) = o;
        }
        // block reduction of csum -> partial (one writer per cell, deterministic)
        int lane = tid & 63, wv = tid >> 6;
        #pragma unroll
        for (int j = 0; j < 8; j++)
            for (int o2 = 32; o2; o2 >>= 1) csum[j] += __shfl_xor(csum[j], o2);
        if (lane == 0) {
            #pragma unroll
            for (int j = 0; j < 8; j++) wsum[wv][j] = csum[j];
        }
        __syncthreads();
        if (tid < 8) {
            float s = wsum[0][tid] + wsum[1][tid] + wsum[2][tid] + wsum[3][tid];
            partial[((size_t)(b * 16 + ty * 4 + tx) * 24 + cg) * 8 + tid] = s;
        }
    }
}

// ---------------- Global mean finish + hg = h_w @ gelu(mean) -------------------
__global__ __launch_bounds__(256) void gmean2_kernel(const float* __restrict__ partial,
                                                     const float* __restrict__ h_w,
                                                     float* __restrict__ hg) {
    __shared__ float ctxg[BB * CC];
    for (int t = threadIdx.x; t < BB * CC; t += 256) {
        int b = t / CC, c = t % CC;
        float s = 0.0f;
        #pragma unroll
        for (int k = 0; k < 16; k++) s += partial[(size_t)(b * 16 + k) * 192 + c];
        ctxg[t] = gelu_f(s * (1.0f / 16384.0f));
    }
    __syncthreads();
    for (int t = threadIdx.x; t < BB * CC; t += 256) {
        int b = t / CC, o = t % CC;
        float s = 0.0f;
        for (int c2 = 0; c2 < CC; c2++) s += h_w[o * CC + c2] * ctxg[b * CC + c2];
        hg[t] = s;
    }
}

// ---------------- fc1: hid = gelu(ln2 @ w1 + b1), 128x128 tile, 8 waves -------
__global__ __launch_bounds__(512, 4) void fc1_kernel(const us16* __restrict__ A,
        const us16* __restrict__ w1T, const float* __restrict__ bias,
        us16* __restrict__ hid0, us16* __restrict__ hid1) {
    __shared__ __align__(16) char Asm[128 * 384];
    int id  = blockIdx.x;
    int swz = (id & 7) * 384 + (id >> 3);   // XCD-chunked: m-contiguous per XCD
    int mt  = swz / 6, nt = swz % 6;
    int m0 = mt * 128;
    int n0 = nt * 128;
    int tid = threadIdx.x, lane = tid & 63, w = tid >> 6;
    int wm = w >> 2, wn = w & 3, g = lane >> 4, lr = lane & 15;

    const char* Agl = (const char*)(A + (size_t)m0 * CC);
    #pragma unroll
    for (int i = 0; i < 6; i++) {
        int wl   = w * 6 + i;                  // 0..47
        int byte = wl * 1024 + lane * 16;
        int row  = byte / 384;
        int off  = byte - row * 384;
        int soff = off ^ ((row & 7) << 4);
        gload_lds16(Agl + (size_t)row * 384 + soff, Asm + wl * 1024);
    }
    const us16* Bb = w1T + (size_t)(n0 + wn * 32 + lr) * CC;
    bf16x8 bfr[6][2];
    #pragma unroll
    for (int kk = 0; kk < 6; kk++)
        #pragma unroll
        for (int j = 0; j < 2; j++)
            bfr[kk][j] = *(const bf16x8*)(Bb + (size_t)j * 16 * CC + kk * 32 + g * 8);

    __syncthreads();

    f32x4 acc[4][2] = {};
    #pragma unroll
    for (int kk = 0; kk < 6; kk++) {
        int k2 = (kk * 32 + g * 8) * 2;
        bf16x8 a[4];
        #pragma unroll
        for (int i = 0; i < 4; i++) {
            int row = wm * 64 + i * 16 + lr;
            a[i] = *(const bf16x8*)(Asm + row * 384 + (k2 ^ ((row & 7) << 4)));
        }
        #pragma unroll
        for (int j = 0; j < 2; j++) {
            acc[0][j] = __builtin_amdgcn_mfma_f32_16x16x32_bf16(a[0], bfr[kk][j], acc[0][j], 0, 0, 0);
            acc[1][j] = __builtin_amdgcn_mfma_f32_16x16x32_bf16(a[1], bfr[kk][j], acc[1][j], 0, 0, 0);
            acc[2][j] = __builtin_amdgcn_mfma_f32_16x16x32_bf16(a[2], bfr[kk][j], acc[2][j], 0, 0, 0);
            acc[3][j] = __builtin_amdgcn_mfma_f32_16x16x32_bf16(a[3], bfr[kk][j], acc[3][j], 0, 0, 0);
        }
    }
    us16* hidp = (m0 & 32768) ? hid1 : hid0;
    int ml = (m0 & 32767) + wm * 64;
    #pragma unroll
    for (int i = 0; i < 4; i++) {
        #pragma unroll
        for (int j = 0; j < 2; j++) {
            int col = n0 + wn * 32 + j * 16 + lr;
            float fb = bias[col];
            #pragma unroll
            for (int r = 0; r < 4; r++) {
                int row = ml + i * 16 + g * 4 + r;
                hidp[(size_t)row * HIDN + col] = f2bf(gelu_f(acc[i][j][r] + fb));
            }
        }
    }
}

// ---------------- fc2: out += hid @ w2 + b2, 128x192 tile, K=768 in 4 chunks --
__global__ __launch_bounds__(512, 4) void fc2_kernel(const us16* __restrict__ hid0,
        const us16* __restrict__ hid1, const us16* __restrict__ w2T,
        const float* __restrict__ bias, float* __restrict__ io) {
    __shared__ __align__(16) char Asm[128 * 384];
    int m0 = blockIdx.x * 128;
    int tid = threadIdx.x, lane = tid & 63, w = tid >> 6;
    int wm = w >> 2, wn = w & 3, g = lane >> 4, lr = lane & 15;
    const us16* hidp = (m0 & 32768) ? hid1 : hid0;
    const char* Agl = (const char*)(hidp + (size_t)(m0 & 32767) * HIDN);

    f32x4 acc[4][3] = {};
    for (int c = 0; c < 4; c++) {
        #pragma unroll
        for (int i = 0; i < 6; i++) {
            int wl   = w * 6 + i;
            int byte = wl * 1024 + lane * 16;
            int row  = byte / 384;
            int off  = byte - row * 384;
            int soff = off ^ ((row & 7) << 4);
            gload_lds16(Agl + (size_t)row * 1536 + c * 384 + soff, Asm + wl * 1024);
        }
        __syncthreads();                       // DMA drained (vmcnt 0)
        #pragma unroll
        for (int kk = 0; kk < 6; kk++) {
            int k2 = (kk * 32 + g * 8) * 2;
            bf16x8 a[4];
            #pragma unroll
            for (int i = 0; i < 4; i++) {
                int row = wm * 64 + i * 16 + lr;
                a[i] = *(const bf16x8*)(Asm + row * 384 + (k2 ^ ((row & 7) << 4)));
            }
            #pragma unroll
            for (int j = 0; j < 3; j++) {
                bf16x8 bv = *(const bf16x8*)(w2T + (size_t)(wn * 48 + j * 16 + lr) * HIDN
                                             + c * 192 + kk * 32 + g * 8);
                acc[0][j] = __builtin_amdgcn_mfma_f32_16x16x32_bf16(a[0], bv, acc[0][j], 0, 0, 0);
                acc[1][j] = __builtin_amdgcn_mfma_f32_16x16x32_bf16(a[1], bv, acc[1][j], 0, 0, 0);
                acc[2][j] = __builtin_amdgcn_mfma_f32_16x16x32_bf16(a[2], bv, acc[2][j], 0, 0, 0);
                acc[3][j] = __builtin_amdgcn_mfma_f32_16x16x32_bf16(a[3], bv, acc[3][j], 0, 0, 0);
            }
        }
        __syncthreads();                       // safe to overwrite Asm
    }
    #pragma unroll
    for (int i = 0; i < 4; i++) {
        #pragma unroll
        for (int j = 0; j < 3; j++) {
            int col = wn * 48 + j * 16 + lr;
            float fb = bias[col];
            #pragma unroll
            for (int r = 0; r < 4; r++) {
                int row = m0 + wm * 64 + i * 16 + g * 4 + r;
                io[(size_t)row * CC + col] += acc[i][j][r] + fb;
            }
        }
    }
}

extern "C" void kernel_launch(void* const* d_in, const int* in_sizes, int n_in,
                              void* d_out, int out_size, void* d_ws, size_t ws_size,
                              hipStream_t stream) {
    const float* x      = (const float*)d_in[0];
    const float* ln1_g  = (const float*)d_in[1];
    const float* ln1_b  = (const float*)d_in[2];
    const float* f_w    = (const float*)d_in[3];
    const float* f_b    = (const float*)d_in[4];
    const float* fk0    = (const float*)d_in[5];
    const float* fk1    = (const float*)d_in[6];
    const float* fk2    = (const float*)d_in[7];
    const float* h_w    = (const float*)d_in[8];
    const float* h_b    = (const float*)d_in[9];
    const float* proj_w = (const float*)d_in[10];
    const float* proj_b = (const float*)d_in[11];
    const float* ln2_g  = (const float*)d_in[12];
    const float* ln2_b  = (const float*)d_in[13];
    const float* fc1_w  = (const float*)d_in[14];
    const float* fc1_b  = (const float*)d_in[15];
    const float* fc2_w  = (const float*)d_in[16];
    const float* fc2_b  = (const float*)d_in[17];
    float* outp = (float*)d_out;

    char* ws = (char*)d_ws;
    const size_t S = (size_t)MM * CC * 2;          // 50,331,648 B (one bf16 plane)
    us16* t_buf   = (us16*)(ws);                   // t / xq ; later hid plane 0
    us16* q_buf   = (us16*)(ws + S);               // q ; later ln2 output
    us16* ctx_all = (us16*)(ws + 2 * S);           // ctx_all ; later hid plane 1
    us16* gates   = (us16*)(ws + 3 * S);
    float* partial = (float*)(ws + 3 * S + 1048576);
    float* hg      = partial + 3072 * 8;
    us16* fwT   = (us16*)(ws + 3 * S + 1048576 + 786432 + 6144);
    us16* hwB   = fwT + 86016;
    us16* projT = hwB + 36864;
    us16* w1T   = projT + 36864;
    us16* w2T   = w1T + 147456;
    us16* kw0T  = w2T + 147456;
    us16* kw1T  = kw0T + 1728;
    us16* kw2T  = kw1T + 4800;
    // conv input plane lives in d_out (dead until mgemm<2> rewrites it fully)
    us16* ctxA = (us16*)d_out;

    wcvt_kernel<<<1839, 256, 0, stream>>>(f_w, h_w, proj_w, fc1_w, fc2_w,
                                          fk0, fk1, fk2,
                                          fwT, hwB, projT, w1T, w2T, kw0T, kw1T, kw2T);

    ln_kernel<<<MM / 4, 256, 0, stream>>>(x, ln1_g, ln1_b, t_buf);

    mgemm_kernel<0><<<8 * 128 * 7, 256, 0, stream>>>(
        t_buf, fwT, f_b, q_buf, ctxA, gates, nullptr, nullptr, nullptr, nullptr, nullptr);

    fconv_kernel<<<3072, 256, 0, stream>>>(ctxA, ctx_all, gates,
                                           kw0T, kw1T, kw2T, partial);

    gmean2_kernel<<<1, 256, 0, stream>>>(partial, h_w, hg);

    mgemm_kernel<1><<<8 * 128 * 3, 256, 0, stream>>>(
        ctx_all, hwB, h_b, t_buf, nullptr, nullptr, q_buf, gates, hg, nullptr, nullptr);

    mgemm_kernel<2><<<8 * 128 * 3, 256, 0, stream>>>(
        t_buf, projT, proj_b, nullptr, nullptr, nullptr, nullptr, nullptr, nullptr, x, outp);

    // ---- MLP as two staged GEMMs over two M-halves ----
    ln_kernel<<<MM / 4, 256, 0, stream>>>(outp, ln2_g, ln2_b, q_buf);

    for (int h = 0; h < 2; h++) {
        const us16* Ah = q_buf + (size_t)h * 65536 * CC;
        float* ioh     = outp  + (size_t)h * 65536 * CC;
        fc1_kernel<<<3072, 512, 0, stream>>>(Ah, w1T, fc1_b, t_buf, ctx_all);
        fc2_kernel<<<512, 512, 0, stream>>>(t_buf, ctx_all, w2T, fc2_b, ioh);
    }
}

// Round 8
// 738.881 us; speedup vs baseline: 4.6618x; 4.6618x over previous
//
#include <hip/hip_runtime.h>
#include <hip/hip_bf16.h>

#define BB   8
#define HGT  128
#define WID  128
#define CC   192
#define LLEN (HGT*WID)        // 16384
#define MM   (BB*LLEN)        // 131072
#define NF   388              // 2C + FL + 1
#define HIDN 768

typedef unsigned short us16;
typedef __attribute__((ext_vector_type(8))) short bf16x8;
typedef __attribute__((ext_vector_type(4))) float f32x4;

__device__ __forceinline__ float bf2f(us16 u) {
    return __uint_as_float(((unsigned int)u) << 16);
}
__device__ __forceinline__ us16 f2bf(float f) {
    unsigned int x = __float_as_uint(f);
    x = (x + 0x7fffu + ((x >> 16) & 1u)) >> 16;
    return (us16)x;
}
// fast gelu: tanh form via exp2-backed __expf
__device__ __forceinline__ float gelu_f(float x) {
    float u = 0.7978845608f * x * (1.0f + 0.044715f * x * x);
    float e = __expf(fminf(2.0f * u, 30.0f));
    return 0.5f * x * (1.0f + (e - 1.0f) / (e + 1.0f));
}

__device__ __forceinline__ void gload_lds16(const void* g, void* l) {
    __builtin_amdgcn_global_load_lds(
        (const __attribute__((address_space(1))) void*)g,
        (__attribute__((address_space(3))) void*)l, 16, 0, 0);
}

// ---------------- Weight convert: fp32 -> bf16, transposed ----------
__global__ __launch_bounds__(256) void wcvt_kernel(const float* __restrict__ f_w,
        const float* __restrict__ h_w, const float* __restrict__ proj_w,
        const float* __restrict__ fc1_w, const float* __restrict__ fc2_w,
        const float* __restrict__ fk0, const float* __restrict__ fk1,
        const float* __restrict__ fk2,
        us16* __restrict__ fwT, us16* __restrict__ hwB, us16* __restrict__ projT,
        us16* __restrict__ w1T, us16* __restrict__ w2T,
        us16* __restrict__ kw0T, us16* __restrict__ kw1T, us16* __restrict__ kw2T) {
    int i = blockIdx.x * 256 + threadIdx.x;
    if (i < 86016) {                       // fwT: 448 x 192 (pad rows >= 388 = 0)
        int n = i / 192, k = i % 192;
        fwT[i] = (n < NF) ? f2bf(f_w[k * NF + n]) : (us16)0;
        return;
    }
    i -= 86016;
    if (i < 36864) { hwB[i] = f2bf(h_w[i]); return; }       // h_w[o][c] is already [N][K]
    i -= 36864;
    if (i < 36864) { int n = i / 192, k = i % 192; projT[i] = f2bf(proj_w[k * CC + n]); return; }
    i -= 36864;
    if (i < 147456) { int n = i / 192, k = i % 192; w1T[i] = f2bf(fc1_w[k * HIDN + n]); return; }
    i -= 147456;
    if (i < 147456) { int n = i / 768, k = i % 768; w2T[i] = f2bf(fc2_w[k * CC + n]); return; }
    i -= 147456;
    if (i < 1728)  { int kyx = i / 192, c = i % 192; kw0T[i] = f2bf(fk0[c * 9 + kyx]);  return; }
    i -= 1728;
    if (i < 4800)  { int kyx = i / 192, c = i % 192; kw1T[i] = f2bf(fk1[c * 25 + kyx]); return; }
    i -= 4800;
    if (i < 9408)  { int kyx = i / 192, c = i % 192; kw2T[i] = f2bf(fk2[c * 49 + kyx]); return; }
}

// ---------------- LayerNorm: fp32 in -> bf16 out (wave per row) ----------------
__global__ __launch_bounds__(256) void ln_kernel(const float* __restrict__ in,
                                                 const float* __restrict__ g,
                                                 const float* __restrict__ b,
                                                 us16* __restrict__ out) {
    int wid  = threadIdx.x >> 6;
    int lane = threadIdx.x & 63;
    int row  = blockIdx.x * 4 + wid;
    const float* p = in + (size_t)row * CC;
    float v0 = p[lane], v1 = p[lane + 64], v2 = p[lane + 128];
    float s1 = v0 + v1 + v2;
    float s2 = v0*v0 + v1*v1 + v2*v2;
    for (int o = 32; o; o >>= 1) { s1 += __shfl_xor(s1, o); s2 += __shfl_xor(s2, o); }
    float m   = s1 * (1.0f / 192.0f);
    float var = s2 * (1.0f / 192.0f) - m * m;
    float inv = rsqrtf(var + 1e-5f);
    us16* q = out + (size_t)row * CC;
    q[lane]       = f2bf((v0 - m) * inv * g[lane]       + b[lane]);
    q[lane + 64]  = f2bf((v1 - m) * inv * g[lane + 64]  + b[lane + 64]);
    q[lane + 128] = f2bf((v2 - m) * inv * g[lane + 128] + b[lane + 128]);
}

// ---------------- MFMA GEMM: LDS-staged A, K=192, 128x64 tile, 4 waves --------
template<int MODE>
__global__ __launch_bounds__(256) void mgemm_kernel(const us16* __restrict__ A,
        const us16* __restrict__ Bt, const float* __restrict__ bias,
        us16* __restrict__ out_q, us16* __restrict__ out_ctx, us16* __restrict__ out_g,
        const us16* __restrict__ q_in, const us16* __restrict__ gates_in,
        const float* __restrict__ hg, const float* __restrict__ x_in,
        float* __restrict__ out_f) {
    __shared__ __align__(16) char Asm[128 * 384];
    constexpr int NT = (MODE == 0) ? 7 : 3;
    int id  = blockIdx.x;
    int xcd = id & 7;
    int s   = id >> 3;
    int mt  = xcd * 128 + s / NT;          // all N-tiles of an M-tile on one XCD
    int nt  = s % NT;
    int m0 = mt * 128, n0 = nt * 64;
    int tid = threadIdx.x, lane = tid & 63, w = tid >> 6;
    int wm = w >> 1, wn = w & 1, g = lane >> 4, lr = lane & 15;

    const char* Agl = (const char*)(A + (size_t)m0 * CC);
    #pragma unroll
    for (int i = 0; i < 12; i++) {
        int wl   = w * 12 + i;                 // 0..47
        int byte = wl * 1024 + lane * 16;
        int row  = byte / 384;
        int off  = byte - row * 384;
        int soff = off ^ ((row & 7) << 4);
        gload_lds16(Agl + (size_t)row * 384 + soff, Asm + wl * 1024);
    }
    const us16* Bb = Bt + (size_t)(n0 + wn * 32 + lr) * CC;
    bf16x8 bfr[6][2];
    #pragma unroll
    for (int kk = 0; kk < 6; kk++)
        #pragma unroll
        for (int j = 0; j < 2; j++)
            bfr[kk][j] = *(const bf16x8*)(Bb + (size_t)j * 16 * CC + kk * 32 + g * 8);

    __syncthreads();

    f32x4 acc[4][2] = {};
    #pragma unroll
    for (int kk = 0; kk < 6; kk++) {
        int k2 = (kk * 32 + g * 8) * 2;
        bf16x8 a[4];
        #pragma unroll
        for (int i = 0; i < 4; i++) {
            int row = wm * 64 + i * 16 + lr;
            a[i] = *(const bf16x8*)(Asm + row * 384 + (k2 ^ ((row & 7) << 4)));
        }
        #pragma unroll
        for (int j = 0; j < 2; j++) {
            acc[0][j] = __builtin_amdgcn_mfma_f32_16x16x32_bf16(a[0], bfr[kk][j], acc[0][j], 0, 0, 0);
            acc[1][j] = __builtin_amdgcn_mfma_f32_16x16x32_bf16(a[1], bfr[kk][j], acc[1][j], 0, 0, 0);
            acc[2][j] = __builtin_amdgcn_mfma_f32_16x16x32_bf16(a[2], bfr[kk][j], acc[2][j], 0, 0, 0);
            acc[3][j] = __builtin_amdgcn_mfma_f32_16x16x32_bf16(a[3], bfr[kk][j], acc[3][j], 0, 0, 0);
        }
    }
    int orow = m0 + wm * 64;
    #pragma unroll
    for (int i = 0; i < 4; i++) {
        #pragma unroll
        for (int j = 0; j < 2; j++) {
            int ncol = n0 + wn * 32 + j * 16;
            int cc   = ncol + lr;
            #pragma unroll
            for (int r = 0; r < 4; r++) {
                int row = orow + i * 16 + g * 4 + r;
                float v = acc[i][j][r];
                if (MODE == 0) {
                    if (ncol < 192)      out_q[(size_t)row * CC + cc]          = f2bf(v + bias[cc]);
                    else if (ncol < 384) out_ctx[(size_t)row * CC + (cc - 192)] = f2bf(v + bias[cc]);
                    else if (cc < NF)    out_g[(size_t)row * 4 + (cc - 384)]    = f2bf(v + bias[cc]);
                } else if (MODE == 1) {
                    int bidx = row >> 14;
                    float val = v + bias[cc] + bf2f(gates_in[(size_t)row * 4 + 3]) * hg[bidx * CC + cc];
                    val *= bf2f(q_in[(size_t)row * CC + cc]);
                    out_q[(size_t)row * CC + cc] = f2bf(val);
                } else {
                    out_f[(size_t)row * CC + cc] = v + bias[cc] + x_in[(size_t)row * CC + cc];
                }
            }
        }
    }
}

// ---------------- Depthwise conv v3: cg-major lanes (coalesced), fused chain --
// LVL 0 (F=3): out = gelu(conv3(in))                      [writes c3 plane]
// LVL 1 (F=5): out = gelu(conv5(c3)); ctx = g0*c3c + g1*out  [writes c5 + ctx01]
// LVL 2 (F=7): c7 = gelu(conv7(c5)); ctx += g2*c7; block partial sums of c7
template<int F, int LVL>
__global__ __launch_bounds__(256) void convv2_kernel(const us16* __restrict__ in,
                            us16* __restrict__ outp,
                            us16* __restrict__ ctx,
                            const us16* __restrict__ gates,
                            const us16* __restrict__ kwT,
                            float* __restrict__ partial) {
    constexpr int P  = F / 2;
    constexpr int NW = F + 3;          // row vectors per ky: XT + F - 1, XT = 4
    __shared__ __align__(16) us16 kws[F * F * CC];
    __shared__ float psum[256][8];     // used by LVL 2 only
    int tid = threadIdx.x;
    int lb  = (blockIdx.x & 7) * 384 + (blockIdx.x >> 3);  // XCD owns one image
    for (int t = tid; t < F * F * CC / 8; t += 256)
        ((bf16x8*)kws)[t] = ((const bf16x8*)kwT)[t];
    __syncthreads();
    int idx  = lb * 256 + tid;                    // over (MM/4)*24
    int cg   = idx % 24;
    int rest = idx / 24;                          // b*4096 + y*32 + x4
    int x4 = rest & 31;
    int y0 = (rest >> 5) & 127;
    int b  = rest >> 12;
    int x0 = x4 * 4;
    float acc[4][8] = {};
    const us16* inb = in + (size_t)b * LLEN * CC + cg * 8;
    for (int ky = 0; ky < F; ky++) {
        int yy = y0 + ky - P;
        if (yy < 0 || yy > 127) continue;
        const us16* rp = inb + (size_t)yy * WID * CC;
        float rv[NW][8];
        #pragma unroll
        for (int i = 0; i < NW; i++) {
            int xx = x0 - P + i;
            if (xx >= 0 && xx <= 127) {
                bf16x8 v = *(const bf16x8*)(rp + (size_t)xx * CC);
                #pragma unroll
                for (int j = 0; j < 8; j++) rv[i][j] = bf2f((us16)v[j]);
            } else {
                #pragma unroll
                for (int j = 0; j < 8; j++) rv[i][j] = 0.0f;
            }
        }
        #pragma unroll
        for (int kx = 0; kx < F; kx++) {
            bf16x8 wv = *(const bf16x8*)(kws + (ky * F + kx) * CC + cg * 8);
            float w[8];
            #pragma unroll
            for (int j = 0; j < 8; j++) w[j] = bf2f((us16)wv[j]);
            #pragma unroll
            for (int px = 0; px < 4; px++)
                #pragma unroll
                for (int j = 0; j < 8; j++)
                    acc[px][j] += rv[kx + px][j] * w[j];
        }
    }
    int pix = (b * HGT + y0) * WID + x0;
    size_t obase = (size_t)pix * CC + cg * 8;
    if constexpr (LVL == 0) {
        #pragma unroll
        for (int px = 0; px < 4; px++) {
            bf16x8 ov;
            #pragma unroll
            for (int j = 0; j < 8; j++) ov[j] = (short)f2bf(gelu_f(acc[px][j]));
            *(bf16x8*)(outp + obase + (size_t)px * CC) = ov;
        }
    } else if constexpr (LVL == 1) {
        #pragma unroll
        for (int px = 0; px < 4; px++) {
            unsigned gv = *(const unsigned*)(gates + (size_t)(pix + px) * 4);
            float g0 = bf2f((us16)(gv & 0xffffu));
            float g1 = bf2f((us16)(gv >> 16));
            // c3 center = input plane at this output pixel
            bf16x8 c3v = *(const bf16x8*)(inb + ((size_t)y0 * WID + x0 + px) * CC);
            bf16x8 ov, cv;
            #pragma unroll
            for (int j = 0; j < 8; j++) {
                float v5 = gelu_f(acc[px][j]);
                ov[j] = (short)f2bf(v5);
                cv[j] = (short)f2bf(g0 * bf2f((us16)c3v[j]) + g1 * v5);
            }
            *(bf16x8*)(outp + obase + (size_t)px * CC) = ov;
            *(bf16x8*)(ctx  + obase + (size_t)px * CC) = cv;
        }
    } else {
        float csum[8] = {};
        #pragma unroll
        for (int px = 0; px < 4; px++) {
            float g2 = bf2f(gates[(size_t)(pix + px) * 4 + 2]);
            bf16x8 cv = *(const bf16x8*)(ctx + obase + (size_t)px * CC);
            bf16x8 ov;
            #pragma unroll
            for (int j = 0; j < 8; j++) {
                float c7 = gelu_f(acc[px][j]);
                csum[j] += c7;
                ov[j] = (short)f2bf(bf2f((us16)cv[j]) + g2 * c7);
            }
            *(bf16x8*)(ctx + obase + (size_t)px * CC) = ov;
        }
        #pragma unroll
        for (int j = 0; j < 8; j++) psum[tid][j] = csum[j];
        __syncthreads();
        if (tid < 192) {
            int j = tid & 7, cgw = tid >> 3;
            int t0 = (cgw - (lb * 256) % 24) % 24;
            if (t0 < 0) t0 += 24;
            float s = 0.0f;
            for (int t = t0; t < 256; t += 24) s += psum[t][j];
            partial[(size_t)lb * CC + tid] = s;   // c == tid (cgw*8 + j)
        }
    }
}

// ---------------- Global mean finish + hg = h_w @ gelu(mean), 1 block/image ---
__global__ __launch_bounds__(192) void gmean2_kernel(const float* __restrict__ partial,
                                                     const float* __restrict__ h_w,
                                                     float* __restrict__ hg) {
    __shared__ float ctxg[CC];
    int b = blockIdx.x, c = threadIdx.x;
    const float* pb = partial + (size_t)b * 384 * CC + c;
    float s = 0.0f;
    for (int k = 0; k < 384; k++) s += pb[(size_t)k * CC];
    ctxg[c] = gelu_f(s * (1.0f / 16384.0f));
    __syncthreads();
    float a = 0.0f;
    for (int c2 = 0; c2 < CC; c2++) a += h_w[c * CC + c2] * ctxg[c2];
    hg[b * CC + c] = a;
}

// ---------------- fc1: hid = gelu(ln2 @ w1 + b1), 128x128 tile, 8 waves -------
__global__ __launch_bounds__(512, 4) void fc1_kernel(const us16* __restrict__ A,
        const us16* __restrict__ w1T, const float* __restrict__ bias,
        us16* __restrict__ hid0, us16* __restrict__ hid1) {
    __shared__ __align__(16) char Asm[128 * 384];
    int id  = blockIdx.x;
    int swz = (id & 7) * 384 + (id >> 3);   // XCD-chunked: m-contiguous per XCD
    int mt  = swz / 6, nt = swz % 6;
    int m0 = mt * 128;
    int n0 = nt * 128;
    int tid = threadIdx.x, lane = tid & 63, w = tid >> 6;
    int wm = w >> 2, wn = w & 3, g = lane >> 4, lr = lane & 15;

    const char* Agl = (const char*)(A + (size_t)m0 * CC);
    #pragma unroll
    for (int i = 0; i < 6; i++) {
        int wl   = w * 6 + i;                  // 0..47
        int byte = wl * 1024 + lane * 16;
        int row  = byte / 384;
        int off  = byte - row * 384;
        int soff = off ^ ((row & 7) << 4);
        gload_lds16(Agl + (size_t)row * 384 + soff, Asm + wl * 1024);
    }
    const us16* Bb = w1T + (size_t)(n0 + wn * 32 + lr) * CC;
    bf16x8 bfr[6][2];
    #pragma unroll
    for (int kk = 0; kk < 6; kk++)
        #pragma unroll
        for (int j = 0; j < 2; j++)
            bfr[kk][j] = *(const bf16x8*)(Bb + (size_t)j * 16 * CC + kk * 32 + g * 8);

    __syncthreads();

    f32x4 acc[4][2] = {};
    #pragma unroll
    for (int kk = 0; kk < 6; kk++) {
        int k2 = (kk * 32 + g * 8) * 2;
        bf16x8 a[4];
        #pragma unroll
        for (int i = 0; i < 4; i++) {
            int row = wm * 64 + i * 16 + lr;
            a[i] = *(const bf16x8*)(Asm + row * 384 + (k2 ^ ((row & 7) << 4)));
        }
        #pragma unroll
        for (int j = 0; j < 2; j++) {
            acc[0][j] = __builtin_amdgcn_mfma_f32_16x16x32_bf16(a[0], bfr[kk][j], acc[0][j], 0, 0, 0);
            acc[1][j] = __builtin_amdgcn_mfma_f32_16x16x32_bf16(a[1], bfr[kk][j], acc[1][j], 0, 0, 0);
            acc[2][j] = __builtin_amdgcn_mfma_f32_16x16x32_bf16(a[2], bfr[kk][j], acc[2][j], 0, 0, 0);
            acc[3][j] = __builtin_amdgcn_mfma_f32_16x16x32_bf16(a[3], bfr[kk][j], acc[3][j], 0, 0, 0);
        }
    }
    us16* hidp = (m0 & 32768) ? hid1 : hid0;
    int ml = (m0 & 32767) + wm * 64;
    #pragma unroll
    for (int i = 0; i < 4; i++) {
        #pragma unroll
        for (int j = 0; j < 2; j++) {
            int col = n0 + wn * 32 + j * 16 + lr;
            float fb = bias[col];
            #pragma unroll
            for (int r = 0; r < 4; r++) {
                int row = ml + i * 16 + g * 4 + r;
                hidp[(size_t)row * HIDN + col] = f2bf(gelu_f(acc[i][j][r] + fb));
            }
        }
    }
}

// ---------------- fc2: out += hid @ w2 + b2, 128x192 tile, K=768 in 4 chunks --
__global__ __launch_bounds__(512, 4) void fc2_kernel(const us16* __restrict__ hid0,
        const us16* __restrict__ hid1, const us16* __restrict__ w2T,
        const float* __restrict__ bias, float* __restrict__ io) {
    __shared__ __align__(16) char Asm[128 * 384];
    int m0 = blockIdx.x * 128;
    int tid = threadIdx.x, lane = tid & 63, w = tid >> 6;
    int wm = w >> 2, wn = w & 3, g = lane >> 4, lr = lane & 15;
    const us16* hidp = (m0 & 32768) ? hid1 : hid0;
    const char* Agl = (const char*)(hidp + (size_t)(m0 & 32767) * HIDN);

    f32x4 acc[4][3] = {};
    for (int c = 0; c < 4; c++) {
        #pragma unroll
        for (int i = 0; i < 6; i++) {
            int wl   = w * 6 + i;
            int byte = wl * 1024 + lane * 16;
            int row  = byte / 384;
            int off  = byte - row * 384;
            int soff = off ^ ((row & 7) << 4);
            gload_lds16(Agl + (size_t)row * 1536 + c * 384 + soff, Asm + wl * 1024);
        }
        __syncthreads();                       // DMA drained (vmcnt 0)
        #pragma unroll
        for (int kk = 0; kk < 6; kk++) {
            int k2 = (kk * 32 + g * 8) * 2;
            bf16x8 a[4];
            #pragma unroll
            for (int i = 0; i < 4; i++) {
                int row = wm * 64 + i * 16 + lr;
                a[i] = *(const bf16x8*)(Asm + row * 384 + (k2 ^ ((row & 7) << 4)));
            }
            #pragma unroll
            for (int j = 0; j < 3; j++) {
                bf16x8 bv = *(const bf16x8*)(w2T + (size_t)(wn * 48 + j * 16 + lr) * HIDN
                                             + c * 192 + kk * 32 + g * 8);
                acc[0][j] = __builtin_amdgcn_mfma_f32_16x16x32_bf16(a[0], bv, acc[0][j], 0, 0, 0);
                acc[1][j] = __builtin_amdgcn_mfma_f32_16x16x32_bf16(a[1], bv, acc[1][j], 0, 0, 0);
                acc[2][j] = __builtin_amdgcn_mfma_f32_16x16x32_bf16(a[2], bv, acc[2][j], 0, 0, 0);
                acc[3][j] = __builtin_amdgcn_mfma_f32_16x16x32_bf16(a[3], bv, acc[3][j], 0, 0, 0);
            }
        }
        __syncthreads();                       // safe to overwrite Asm
    }
    #pragma unroll
    for (int i = 0; i < 4; i++) {
        #pragma unroll
        for (int j = 0; j < 3; j++) {
            int col = wn * 48 + j * 16 + lr;
            float fb = bias[col];
            #pragma unroll
            for (int r = 0; r < 4; r++) {
                int row = m0 + wm * 64 + i * 16 + g * 4 + r;
                io[(size_t)row * CC + col] += acc[i][j][r] + fb;
            }
        }
    }
}

extern "C" void kernel_launch(void* const* d_in, const int* in_sizes, int n_in,
                              void* d_out, int out_size, void* d_ws, size_t ws_size,
                              hipStream_t stream) {
    const float* x      = (const float*)d_in[0];
    const float* ln1_g  = (const float*)d_in[1];
    const float* ln1_b  = (const float*)d_in[2];
    const float* f_w    = (const float*)d_in[3];
    const float* f_b    = (const float*)d_in[4];
    const float* fk0    = (const float*)d_in[5];
    const float* fk1    = (const float*)d_in[6];
    const float* fk2    = (const float*)d_in[7];
    const float* h_w    = (const float*)d_in[8];
    const float* h_b    = (const float*)d_in[9];
    const float* proj_w = (const float*)d_in[10];
    const float* proj_b = (const float*)d_in[11];
    const float* ln2_g  = (const float*)d_in[12];
    const float* ln2_b  = (const float*)d_in[13];
    const float* fc1_w  = (const float*)d_in[14];
    const float* fc1_b  = (const float*)d_in[15];
    const float* fc2_w  = (const float*)d_in[16];
    const float* fc2_b  = (const float*)d_in[17];
    float* outp = (float*)d_out;

    char* ws = (char*)d_ws;
    const size_t S = (size_t)MM * CC * 2;          // 50,331,648 B (one bf16 plane)
    us16* t_buf   = (us16*)(ws);                   // t / xq ; later hid plane 0
    us16* q_buf   = (us16*)(ws + S);               // q ; later ln2 output
    us16* ctx_all = (us16*)(ws + 2 * S);           // ctx01/ctx_all ; later hid plane 1
    us16* gates   = (us16*)(ws + 3 * S);
    float* hg      = (float*)(ws + 3 * S + 1048576);
    us16* fwT   = (us16*)(ws + 3 * S + 1048576 + 786432 + 6144);
    us16* hwB   = fwT + 86016;
    us16* projT = hwB + 36864;
    us16* w1T   = projT + 36864;
    us16* w2T   = w1T + 147456;
    us16* kw0T  = w2T + 147456;
    us16* kw1T  = kw0T + 1728;
    us16* kw2T  = kw1T + 4800;
    // conv planes live in d_out (dead until mgemm<2> rewrites it fully)
    us16* ctxA = (us16*)d_out;                          // conv input, then c5
    us16* ctxB = (us16*)d_out + (size_t)MM * CC;        // c3
    float* partial = (float*)ctxB;                      // reused after c3 is dead

    wcvt_kernel<<<1839, 256, 0, stream>>>(f_w, h_w, proj_w, fc1_w, fc2_w,
                                          fk0, fk1, fk2,
                                          fwT, hwB, projT, w1T, w2T, kw0T, kw1T, kw2T);

    ln_kernel<<<MM / 4, 256, 0, stream>>>(x, ln1_g, ln1_b, t_buf);

    mgemm_kernel<0><<<8 * 128 * 7, 256, 0, stream>>>(
        t_buf, fwT, f_b, q_buf, ctxA, gates, nullptr, nullptr, nullptr, nullptr, nullptr);

    convv2_kernel<3, 0><<<3072, 256, 0, stream>>>(ctxA, ctxB, nullptr, nullptr, kw0T, nullptr);
    convv2_kernel<5, 1><<<3072, 256, 0, stream>>>(ctxB, ctxA, ctx_all, gates, kw1T, nullptr);
    convv2_kernel<7, 2><<<3072, 256, 0, stream>>>(ctxA, nullptr, ctx_all, gates, kw2T, partial);

    gmean2_kernel<<<8, 192, 0, stream>>>(partial, h_w, hg);

    mgemm_kernel<1><<<8 * 128 * 3, 256, 0, stream>>>(
        ctx_all, hwB, h_b, t_buf, nullptr, nullptr, q_buf, gates, hg, nullptr, nullptr);

    mgemm_kernel<2><<<8 * 128 * 3, 256, 0, stream>>>(
        t_buf, projT, proj_b, nullptr, nullptr, nullptr, nullptr, nullptr, nullptr, x, outp);

    // ---- MLP as two staged GEMMs over two M-halves ----
    ln_kernel<<<MM / 4, 256, 0, stream>>>(outp, ln2_g, ln2_b, q_buf);

    for (int h = 0; h < 2; h++) {
        const us16* Ah = q_buf + (size_t)h * 65536 * CC;
        float* ioh     = outp  + (size_t)h * 65536 * CC;
        fc1_kernel<<<3072, 512, 0, stream>>>(Ah, w1T, fc1_b, t_buf, ctx_all);
        fc2_kernel<<<512, 512, 0, stream>>>(t_buf, ctx_all, w2T, fc2_b, ioh);
    }
}